// Round 20
// baseline (131.237 us; speedup 1.0000x reference)
//
#include <hip/hip_runtime.h>
#include <hip/hip_fp16.h>
#include <hip/hip_fp8.h>

#define NN   50000
#define FIN  256
#define C1   64        // HEADS*HID
#define NH   8
#define NC   16
#define NE   1600000
#define NTOT (NE + NN)

#define CH   256                        // pass-1 chunks
#define EPC  ((NTOT + CH - 1) / CH)     // 6446 edges per chunk
#define NCB  196                        // coarse buckets: dst>>8 (256 dsts each)
#define GB1  ((NN + 63) / 64)           // 782 gemm1 blocks

typedef _Float16 half8 __attribute__((ext_vector_type(8)));
typedef _Float16 half4 __attribute__((ext_vector_type(4)));
typedef float f32x4 __attribute__((ext_vector_type(4)));
typedef float floatx2 __attribute__((ext_vector_type(2)));

#if __has_builtin(__builtin_amdgcn_cvt_pk_f32_fp8) && __has_builtin(__builtin_amdgcn_cvt_pk_fp8_f32)
#define FP8_FAST 1
#endif

__device__ __forceinline__ unsigned pack4_fp8(float f0, float f1, float f2, float f3) {
#ifdef FP8_FAST
    int d = 0;
    d = __builtin_amdgcn_cvt_pk_fp8_f32(f0, f1, d, false);
    d = __builtin_amdgcn_cvt_pk_fp8_f32(f2, f3, d, true);
    return (unsigned)d;
#else
    __hip_fp8_e4m3 q0(f0), q1(f1), q2(f2), q3(f3);
    return (unsigned)q0.__x | ((unsigned)q1.__x << 8) |
           ((unsigned)q2.__x << 16) | ((unsigned)q3.__x << 24);
#endif
}

// fp8 x8 -> four packed float2
__device__ __forceinline__ void cvt8_fp8_pk(unsigned lo, unsigned hi,
                                            floatx2* p0, floatx2* p1,
                                            floatx2* p2, floatx2* p3) {
#ifdef FP8_FAST
    *p0 = __builtin_amdgcn_cvt_pk_f32_fp8((int)lo, false);
    *p1 = __builtin_amdgcn_cvt_pk_f32_fp8((int)lo, true);
    *p2 = __builtin_amdgcn_cvt_pk_f32_fp8((int)hi, false);
    *p3 = __builtin_amdgcn_cvt_pk_f32_fp8((int)hi, true);
#else
    float f[8];
    #pragma unroll
    for (int u = 0; u < 4; ++u) {
        __hip_fp8_e4m3 q; q.__x = (unsigned char)((lo >> (8*u)) & 0xff);
        f[u] = (float)q;
        __hip_fp8_e4m3 p; p.__x = (unsigned char)((hi >> (8*u)) & 0xff);
        f[4+u] = (float)p;
    }
    (*p0)[0]=f[0]; (*p0)[1]=f[1]; (*p1)[0]=f[2]; (*p1)[1]=f[3];
    (*p2)[0]=f[4]; (*p2)[1]=f[5]; (*p3)[0]=f[6]; (*p3)[1]=f[7];
#endif
}

// ---- workspace layout (float-indexed), ~36 MB (d_ws is 256 MiB) ----
#define OFF_H1F8  0          // fp8 h1 [NN*64 B] = 800K floats
#define OFF_ALS1H 800000     // fp16 als1 [NN*8] = 200K floats
#define OFF_G1H   1600000    // fp16 g1 [NN*64]
#define OFF_STAGE 3200000
#define OFF_H2H   3200000    // reuses stage after fsort
#define OFF_ALS2  3600000
#define OFF_ALD2  3650000
#define OFF_ALD1  6800000    // f32 ald1 [NN*8]
#define OFF_HM    7200000    // int H[CH*NCB]
#define OFF_BASEK 7300352    // int basek[NCB*CH]
#define OFF_BTOT  7400704    // int btot[NCB]
#define OFF_OFFS  7401600    // int offs[NN+1]
#define OFF_SRC   7451700    // int ssrc[NTOT + 32 sentinel]
// end = 9,101,732 floats = 36.4 MB

// ------- K1: [blocks 0..781] h1=x@W1 MFMA, A direct-to-register; h1 -> fp8
//         [blocks 782..1037] rh: per-chunk coarse histogram
__global__ __launch_bounds__(256) void k_g1rh(const float* __restrict__ x,
                                              const float* __restrict__ W1,
                                              const float* __restrict__ as1,
                                              const float* __restrict__ ad1,
                                              unsigned char* __restrict__ h1f8,
                                              _Float16* __restrict__ als1h,
                                              float* __restrict__ ald,
                                              const int* __restrict__ ei,
                                              int* __restrict__ H) {
    __shared__ _Float16 wsT[64][264];   // [col][k] 33.8 KB; reused as hstore
    __shared__ int lh[NCB];
    const int tid = threadIdx.x;

    if (blockIdx.x >= GB1) {            // ---- rh branch ----
        int k = blockIdx.x - GB1;
        for (int i = tid; i < NCB; i += 256) lh[i] = 0;
        __syncthreads();
        int e0 = k * EPC, e1 = min(e0 + EPC, NTOT);
        for (int e = e0 + tid; e < e1; e += 256) {
            int d = (e < NE) ? ei[NE + e] : (e - NE);
            atomicAdd(&lh[d >> 8], 1);
        }
        __syncthreads();
        for (int i = tid; i < NCB; i += 256) H[k * NCB + i] = lh[i];
        return;
    }

    // ---- gemm1 branch ----
    const int r0 = blockIdx.x * 64;
    {   // stage W1 -> wsT[col][k], coalesced f32 reads, half8 writes
        int c = tid & 63, kb = tid >> 6;
        #pragma unroll
        for (int j = 0; j < 8; ++j) {
            int k8 = kb + 4 * j;
            half8 hv;
            #pragma unroll
            for (int u = 0; u < 8; ++u)
                hv[u] = (_Float16)W1[(size_t)(k8 * 8 + u) * C1 + c];
            *(half8*)(&wsT[c][k8 * 8]) = hv;
        }
    }
    __syncthreads();

    const int lane = tid & 63;
    const int wv   = tid >> 6;
    const int colb = lane & 15;
    const int rgrp = lane >> 4;
    const int arow = r0 + wv * 16 + colb;
    const bool arv = arow < NN;
    f32x4 acc[4] = {};
    #pragma unroll
    for (int s = 0; s < 8; ++s) {
        float4 v0 = make_float4(0.f,0.f,0.f,0.f), v1 = v0;
        if (arv) {
            const float4* xp = (const float4*)(&x[(size_t)arow * FIN + s * 32 + rgrp * 8]);
            v0 = xp[0]; v1 = xp[1];
        }
        half8 a;
        a[0]=(_Float16)v0.x; a[1]=(_Float16)v0.y; a[2]=(_Float16)v0.z; a[3]=(_Float16)v0.w;
        a[4]=(_Float16)v1.x; a[5]=(_Float16)v1.y; a[6]=(_Float16)v1.z; a[7]=(_Float16)v1.w;
        #pragma unroll
        for (int ct = 0; ct < 4; ++ct) {
            half8 b = *(half8*)(&wsT[ct * 16 + colb][s * 32 + rgrp * 8]);
            acc[ct] = __builtin_amdgcn_mfma_f32_16x16x32_f16(a, b, acc[ct], 0, 0, 0);
        }
    }
    __syncthreads();                    // wsT reads done; reuse as hstore
    _Float16 (*hstore)[72] = (_Float16(*)[72])wsT;
    #pragma unroll
    for (int j = 0; j < 4; ++j) {
        int row = wv * 16 + rgrp * 4 + j;
        #pragma unroll
        for (int ct = 0; ct < 4; ++ct)
            hstore[row][ct * 16 + colb] = (_Float16)acc[ct][j];
    }
    __syncthreads();
    {   // coalesced fp8 h1 store + lane-local als(fp16)/ald(f32), 2 heads/lane
        int row = tid >> 2, seg = tid & 3;
        int grow = r0 + row;
        if (grow < NN) {
            half8 h0 = *(half8*)(&hstore[row][seg * 16]);
            half8 h1v = *(half8*)(&hstore[row][seg * 16 + 8]);
            float fv[16];
            #pragma unroll
            for (int u = 0; u < 8; ++u) { fv[u] = (float)h0[u]; fv[8 + u] = (float)h1v[u]; }
            uint4 pk;
            pk.x = pack4_fp8(fv[0],  fv[1],  fv[2],  fv[3]);
            pk.y = pack4_fp8(fv[4],  fv[5],  fv[6],  fv[7]);
            pk.z = pack4_fp8(fv[8],  fv[9],  fv[10], fv[11]);
            pk.w = pack4_fp8(fv[12], fv[13], fv[14], fv[15]);
            *(uint4*)(&h1f8[(size_t)grow * 64 + seg * 16]) = pk;
            float ps0 = 0.f, pd0 = 0.f, ps1 = 0.f, pd1 = 0.f;
            #pragma unroll
            for (int u = 0; u < 8; ++u) {
                ps0 += fv[u]     * as1[seg * 16 + u];
                pd0 += fv[u]     * ad1[seg * 16 + u];
                ps1 += fv[8 + u] * as1[seg * 16 + 8 + u];
                pd1 += fv[8 + u] * ad1[seg * 16 + 8 + u];
            }
            als1h[grow * NH + seg * 2]     = (_Float16)ps0;
            als1h[grow * NH + seg * 2 + 1] = (_Float16)ps1;
            ald[grow * NH + seg * 2]     = pd0;
            ald[grow * NH + seg * 2 + 1] = pd1;
        }
    }
}

// ======== deterministic 2-pass counting sort (no global atomics) =========
__global__ __launch_bounds__(256) void k_rsA(const int* __restrict__ H,
                                             int* __restrict__ basek,
                                             int* __restrict__ btot) {
    __shared__ int sc[CH];
    int b = blockIdx.x, t = threadIdx.x;
    int v = H[t * NCB + b];
    sc[t] = v;
    __syncthreads();
    for (int s = 1; s < CH; s <<= 1) {
        int u = (t >= s) ? sc[t - s] : 0;
        __syncthreads();
        sc[t] += u;
        __syncthreads();
    }
    basek[b * CH + t] = sc[t] - v;
    if (t == CH - 1) btot[b] = sc[t];
}

__global__ __launch_bounds__(256) void k_rscatter(const int* __restrict__ ei,
                                                  const int* __restrict__ basek,
                                                  const int* __restrict__ btot,
                                                  int* __restrict__ stage) {
    __shared__ int sc[256];
    __shared__ int lcur[NCB];
    int k = blockIdx.x, t = threadIdx.x;
    int v = (t < NCB) ? btot[t] : 0;
    sc[t] = v;
    __syncthreads();
    for (int s = 1; s < 256; s <<= 1) {
        int u = (t >= s) ? sc[t - s] : 0;
        __syncthreads();
        sc[t] += u;
        __syncthreads();
    }
    if (t < NCB) lcur[t] = (sc[t] - v) + basek[t * CH + k];
    __syncthreads();
    int e0 = k * EPC, e1 = min(e0 + EPC, NTOT);
    for (int e = e0 + t; e < e1; e += 256) {
        int s, d;
        if (e < NE) { s = ei[e]; d = ei[NE + e]; }
        else        { s = e - NE; d = s; }
        int pos = atomicAdd(&lcur[d >> 8], 1);
        stage[pos] = (s << 8) | (d & 255);
    }
}

__global__ __launch_bounds__(256) void k_fsort(const int* __restrict__ stage,
                                               const int* __restrict__ btot,
                                               int* __restrict__ offs,
                                               int* __restrict__ ssrc) {
    __shared__ int sc[256];
    __shared__ int lc[256];
    __shared__ int ls[256];
    __shared__ int lcur[256];
    __shared__ int bb[2];
    int b = blockIdx.x, t = threadIdx.x;
    int v = (t < NCB) ? btot[t] : 0;
    sc[t] = v;
    __syncthreads();
    for (int s = 1; s < 256; s <<= 1) {
        int u = (t >= s) ? sc[t - s] : 0;
        __syncthreads();
        sc[t] += u;
        __syncthreads();
    }
    if (t == b) { bb[0] = sc[t] - v; bb[1] = sc[t]; }
    if (b == 0 && t == 0) offs[NN] = NTOT;
    if (b == 0 && t < 32) ssrc[NTOT + t] = 0;   // sentinel pad: node 0
    lc[t] = 0;
    __syncthreads();
    int base = bb[0];
    int n = bb[1] - base;
    const int* sp = &stage[base];
    for (int i = t; i < n; i += 256) atomicAdd(&lc[sp[i] & 255], 1);
    __syncthreads();
    int hv = lc[t];
    ls[t] = hv;
    __syncthreads();
    for (int s = 1; s < 256; s <<= 1) {
        int u = (t >= s) ? ls[t - s] : 0;
        __syncthreads();
        ls[t] += u;
        __syncthreads();
    }
    int excl = ls[t] - hv;
    int d = b * 256 + t;
    if (d < NN) offs[d] = base + excl;
    lcur[t] = base + excl;
    __syncthreads();
    for (int i = t; i < n; i += 256) {
        int u = sp[i];
        int pos = atomicAdd(&lcur[u & 255], 1);
        ssrc[pos] = u >> 8;
    }
}

// ------- K2: layer-1 aggregation, fp8 gathers (L2-resident), packed-f32 FMA,
//             sentinel-padded src (unconditional gather addresses) ----------
__global__ __launch_bounds__(256) void k_agg1(const int* __restrict__ offs,
                                              const int* __restrict__ src,
                                              const unsigned char* __restrict__ h1f8,
                                              const _Float16* __restrict__ als1h,
                                              const float* __restrict__ ald,
                                              const float* __restrict__ b1,
                                              _Float16* __restrict__ g1h) {
    int d = blockIdx.x * 4 + (threadIdx.x >> 6);
    if (d >= NN) return;
    const int l = threadIdx.x & 63;
    const int slot = l >> 3, hd = l & 7;
    const unsigned coff = (unsigned)hd * 8u;    // byte offset in h1f8 row (64 B)
    int beg = offs[d], end = offs[d + 1];
    float aldv = ald[d * NH + hd];
    floatx2 acc2[4] = {};
    float wsum = 0.f;

    for (int r = beg; r < end; r += 16) {
        int e0 = r + slot, e1 = e0 + 8;
        int s0 = src[e0];                       // sentinel-padded: no clamp
        int s1 = src[e1];
        uint2 q0 = *(const uint2*)(h1f8 + ((unsigned)s0 * 64u + coff));
        uint2 q1 = *(const uint2*)(h1f8 + ((unsigned)s1 * 64u + coff));
        float lg0 = (float)als1h[s0 * NH + hd] + aldv;
        float lg1 = (float)als1h[s1 * NH + hd] + aldv;
        lg0 = fmaxf(lg0, 0.2f * lg0);           // leaky_relu, 1 op
        lg1 = fmaxf(lg1, 0.2f * lg1);
        float w0 = (e0 < end) ? __expf(lg0) : 0.f;
        float w1 = (e1 < end) ? __expf(lg1) : 0.f;
        wsum += w0 + w1;
        floatx2 a0, a1, a2, a3, c0, c1, c2, c3;
        cvt8_fp8_pk(q0.x, q0.y, &a0, &a1, &a2, &a3);
        cvt8_fp8_pk(q1.x, q1.y, &c0, &c1, &c2, &c3);
        floatx2 w0v = {w0, w0}, w1v = {w1, w1};
        acc2[0] += w0v * a0 + w1v * c0;
        acc2[1] += w0v * a1 + w1v * c1;
        acc2[2] += w0v * a2 + w1v * c2;
        acc2[3] += w0v * a3 + w1v * c3;
    }
    float acc[8];
    #pragma unroll
    for (int u = 0; u < 4; ++u) { acc[2*u] = acc2[u][0]; acc[2*u+1] = acc2[u][1]; }
    #pragma unroll
    for (int u = 0; u < 8; ++u) {
        acc[u] += __shfl_xor(acc[u], 8);
        acc[u] += __shfl_xor(acc[u], 16);
        acc[u] += __shfl_xor(acc[u], 32);
    }
    wsum += __shfl_xor(wsum, 8);
    wsum += __shfl_xor(wsum, 16);
    wsum += __shfl_xor(wsum, 32);
    if (slot == 0) {
        half8 gv;
        #pragma unroll
        for (int u = 0; u < 8; ++u) {
            float o = acc[u] / wsum + b1[hd * 8 + u];
            o = o > 0.f ? o : (__expf(o) - 1.f);
            gv[u] = (_Float16)o;
        }
        *(half8*)(&g1h[(size_t)d * C1 + hd * 8]) = gv;
    }
}

// ---------------- K3: GEMM2 (64->16, fp16 in) + layer-2 logits ----------------
__global__ __launch_bounds__(256) void k_gemm2(const _Float16* __restrict__ g1h,
                                               const float* __restrict__ W2,
                                               const float* __restrict__ as2,
                                               const float* __restrict__ ad2,
                                               _Float16* __restrict__ h2h,
                                               float* __restrict__ als2,
                                               float* __restrict__ ald2) {
    __shared__ float w2s[C1][17];
    __shared__ _Float16 hact[16][C1 + 8];
    int tid = threadIdx.x;
    for (int i = tid; i < C1 * NC; i += 256) w2s[i >> 4][i & 15] = W2[i];
    int ln = tid >> 4, j = tid & 15;
    int n = blockIdx.x * 16 + ln;
    if (n < NN)
        *(half4*)(&hact[ln][j * 4]) = *(const half4*)(&g1h[(size_t)n * C1 + j * 4]);
    __syncthreads();
    if (n >= NN) return;
    float sum = 0.f;
    #pragma unroll
    for (int c = 0; c < C1; ++c) sum += (float)hact[ln][c] * w2s[c][j];
    h2h[(size_t)n * NC + j] = (_Float16)sum;
    float ps = sum * as2[j], pd = sum * ad2[j];
    #pragma unroll
    for (int w = 1; w < 16; w <<= 1) {
        ps += __shfl_xor(ps, w);
        pd += __shfl_xor(pd, w);
    }
    if (j == 0) { als2[n] = ps; ald2[n] = pd; }
}

// ------- K4: layer-2 aggregation, shuffle-free, sentinel-padded src,
//             fused log_softmax --------------------------------------------
__global__ __launch_bounds__(256) void k_agg2(const int* __restrict__ offs,
                                              const int* __restrict__ src,
                                              const _Float16* __restrict__ h2h,
                                              const float* __restrict__ als2,
                                              const float* __restrict__ ald2,
                                              const float* __restrict__ b2,
                                              float* __restrict__ out) {
    int d = blockIdx.x * 4 + (threadIdx.x >> 6);
    if (d >= NN) return;
    const int l = threadIdx.x & 63;
    const int slot = l >> 2, cq = l & 3;
    const unsigned coff = (unsigned)cq * 8u;
    const char* h2b = (const char*)h2h;
    const char* alb = (const char*)als2;
    int beg = offs[d], end = offs[d + 1];
    float aldv = ald2[d];
    float acc[4] = {};
    float wsum = 0.f;
    for (int r = beg; r < end; r += 16) {
        int e = r + slot;
        int s = src[e];                          // sentinel-padded: no clamp
        half4 hv = *(const half4*)(h2b + ((unsigned)s * 32u + coff));
        float lg = *(const float*)(alb + (unsigned)s * 4u) + aldv;
        lg = fmaxf(lg, 0.2f * lg);
        float w = (e < end) ? __expf(lg) : 0.f;
        wsum += w;
        #pragma unroll
        for (int u = 0; u < 4; ++u)
            acc[u] += w * (float)hv[u];
    }
    #pragma unroll
    for (int u = 0; u < 4; ++u) {
        acc[u] += __shfl_xor(acc[u], 4);
        acc[u] += __shfl_xor(acc[u], 8);
        acc[u] += __shfl_xor(acc[u], 16);
        acc[u] += __shfl_xor(acc[u], 32);
    }
    wsum += __shfl_xor(wsum, 4);
    wsum += __shfl_xor(wsum, 8);
    wsum += __shfl_xor(wsum, 16);
    wsum += __shfl_xor(wsum, 32);
    float o[4];
    float m = -1e30f;
    #pragma unroll
    for (int u = 0; u < 4; ++u) {
        o[u] = acc[u] / wsum + b2[cq * 4 + u];
        m = fmaxf(m, o[u]);
    }
    m = fmaxf(m, __shfl_xor(m, 1));
    m = fmaxf(m, __shfl_xor(m, 2));
    float sm = 0.f;
    #pragma unroll
    for (int u = 0; u < 4; ++u) sm += __expf(o[u] - m);
    sm += __shfl_xor(sm, 1);
    sm += __shfl_xor(sm, 2);
    float lse = m + __logf(sm);
    if (slot == 0) {
        float4 ov = make_float4(o[0] - lse, o[1] - lse, o[2] - lse, o[3] - lse);
        *(float4*)(&out[(size_t)d * NC + cq * 4]) = ov;
    }
}

extern "C" void kernel_launch(void* const* d_in, const int* in_sizes, int n_in,
                              void* d_out, int out_size, void* d_ws, size_t ws_size,
                              hipStream_t stream) {
    const float* x   = (const float*)d_in[0];
    const int*   ei  = (const int*)  d_in[1];
    const float* W1  = (const float*)d_in[2];
    const float* as1 = (const float*)d_in[3];
    const float* ad1 = (const float*)d_in[4];
    const float* b1  = (const float*)d_in[5];
    const float* W2  = (const float*)d_in[6];
    const float* as2 = (const float*)d_in[7];
    const float* ad2 = (const float*)d_in[8];
    const float* b2  = (const float*)d_in[9];
    float* ws  = (float*)d_ws;
    float* out = (float*)d_out;

    unsigned char* h1f8 = (unsigned char*)(ws + OFF_H1F8);
    _Float16*  als1h = (_Float16*)(ws + OFF_ALS1H);
    _Float16*  g1h  = (_Float16*)(ws + OFF_G1H);
    _Float16*  h2h  = (_Float16*)(ws + OFF_H2H);
    float* ald1 = ws + OFF_ALD1;
    float* als2 = ws + OFF_ALS2;
    float* ald2 = ws + OFF_ALD2;
    int* H      = (int*)(ws + OFF_HM);
    int* basek  = (int*)(ws + OFF_BASEK);
    int* btot   = (int*)(ws + OFF_BTOT);
    int* offs   = (int*)(ws + OFF_OFFS);
    int* ssrc   = (int*)(ws + OFF_SRC);
    int* stage  = (int*)(ws + OFF_STAGE);

    k_g1rh    <<<GB1 + CH,       256, 0, stream>>>(x, W1, as1, ad1, h1f8, als1h, ald1, ei, H);
    k_rsA     <<<NCB,            256, 0, stream>>>(H, basek, btot);
    k_rscatter<<<CH,             256, 0, stream>>>(ei, basek, btot, stage);
    k_fsort   <<<NCB,            256, 0, stream>>>(stage, btot, offs, ssrc);
    k_agg1    <<<(NN + 3) / 4,   256, 0, stream>>>(offs, ssrc, h1f8, als1h, ald1, b1, g1h);
    k_gemm2   <<<(NN + 15) / 16, 256, 0, stream>>>(g1h, W2, as2, ad2, h2h, als2, ald2);
    k_agg2    <<<(NN + 3) / 4,   256, 0, stream>>>(offs, ssrc, h2h, als2, ald2, b2, out);
}

// Round 21
// 123.565 us; speedup vs baseline: 1.0621x; 1.0621x over previous
//
#include <hip/hip_runtime.h>
#include <hip/hip_fp16.h>
#include <hip/hip_fp8.h>

#define NN   50000
#define FIN  256
#define C1   64        // HEADS*HID
#define NH   8
#define NC   16
#define NE   1600000
#define NTOT (NE + NN)

#define CH   1024                       // pass-1 chunks (4 blocks/CU)
#define EPC  ((NTOT + CH - 1) / CH)     // 1612 edges per chunk
#define NCB  392                        // coarse buckets: dst>>7 (128 dsts each)
#define GB1  ((NN + 63) / 64)           // 782 gemm1 blocks

typedef _Float16 half8 __attribute__((ext_vector_type(8)));
typedef _Float16 half4 __attribute__((ext_vector_type(4)));
typedef float f32x4 __attribute__((ext_vector_type(4)));
typedef float floatx2 __attribute__((ext_vector_type(2)));

#if __has_builtin(__builtin_amdgcn_cvt_pk_f32_fp8) && __has_builtin(__builtin_amdgcn_cvt_pk_fp8_f32)
#define FP8_FAST 1
#endif

__device__ __forceinline__ unsigned pack4_fp8(float f0, float f1, float f2, float f3) {
#ifdef FP8_FAST
    int d = 0;
    d = __builtin_amdgcn_cvt_pk_fp8_f32(f0, f1, d, false);
    d = __builtin_amdgcn_cvt_pk_fp8_f32(f2, f3, d, true);
    return (unsigned)d;
#else
    __hip_fp8_e4m3 q0(f0), q1(f1), q2(f2), q3(f3);
    return (unsigned)q0.__x | ((unsigned)q1.__x << 8) |
           ((unsigned)q2.__x << 16) | ((unsigned)q3.__x << 24);
#endif
}

// fp8 x8 -> four packed float2
__device__ __forceinline__ void cvt8_fp8_pk(unsigned lo, unsigned hi,
                                            floatx2* p0, floatx2* p1,
                                            floatx2* p2, floatx2* p3) {
#ifdef FP8_FAST
    *p0 = __builtin_amdgcn_cvt_pk_f32_fp8((int)lo, false);
    *p1 = __builtin_amdgcn_cvt_pk_f32_fp8((int)lo, true);
    *p2 = __builtin_amdgcn_cvt_pk_f32_fp8((int)hi, false);
    *p3 = __builtin_amdgcn_cvt_pk_f32_fp8((int)hi, true);
#else
    float f[8];
    #pragma unroll
    for (int u = 0; u < 4; ++u) {
        __hip_fp8_e4m3 q; q.__x = (unsigned char)((lo >> (8*u)) & 0xff);
        f[u] = (float)q;
        __hip_fp8_e4m3 p; p.__x = (unsigned char)((hi >> (8*u)) & 0xff);
        f[4+u] = (float)p;
    }
    (*p0)[0]=f[0]; (*p0)[1]=f[1]; (*p1)[0]=f[2]; (*p1)[1]=f[3];
    (*p2)[0]=f[4]; (*p2)[1]=f[5]; (*p3)[0]=f[6]; (*p3)[1]=f[7];
#endif
}

// ---- workspace layout (float-indexed), ~40 MB (d_ws is 256 MiB) ----
#define OFF_H1F8  0          // fp8 h1 [NN*64 B] = 800K floats
#define OFF_ALS1H 800000     // fp16 als1 [NN*8] = 200K floats
#define OFF_G1H   1600000    // fp16 g1 [NN*64]
#define OFF_STAGE 3200000
#define OFF_H2H   3200000    // reuses stage after fsort
#define OFF_ALS2  3600000
#define OFF_ALD2  3650000
#define OFF_ALD1  6800000    // f32 ald1 [NN*8]
#define OFF_HM    7200000    // int H[CH*NCB] = 401,408
#define OFF_BASEK 7700000    // int basek[NCB*CH] = 401,408
#define OFF_BTOT  8200000    // int btot[NCB]
#define OFF_OFFS  8201000    // int offs[NN+1]
#define OFF_SRC   8260000    // int ssrc[NTOT + 32 sentinel]
// end = 9,910,032 floats = 39.6 MB

// ------- K1: [blocks 0..781] h1=x@W1 MFMA, A direct-to-register; h1 -> fp8
//         [blocks 782..1805] rh: per-chunk coarse histogram (dst>>7)
__global__ __launch_bounds__(256) void k_g1rh(const float* __restrict__ x,
                                              const float* __restrict__ W1,
                                              const float* __restrict__ as1,
                                              const float* __restrict__ ad1,
                                              unsigned char* __restrict__ h1f8,
                                              _Float16* __restrict__ als1h,
                                              float* __restrict__ ald,
                                              const int* __restrict__ ei,
                                              int* __restrict__ H) {
    __shared__ _Float16 wsT[64][264];   // [col][k] 33.8 KB; reused as hstore
    __shared__ int lh[NCB];             // 1.6 KB
    const int tid = threadIdx.x;

    if (blockIdx.x >= GB1) {            // ---- rh branch ----
        int k = blockIdx.x - GB1;
        for (int i = tid; i < NCB; i += 256) lh[i] = 0;
        __syncthreads();
        int e0 = k * EPC, e1 = min(e0 + EPC, NTOT);
        for (int e = e0 + tid; e < e1; e += 256) {
            int d = (e < NE) ? ei[NE + e] : (e - NE);
            atomicAdd(&lh[d >> 7], 1);
        }
        __syncthreads();
        for (int i = tid; i < NCB; i += 256) H[(size_t)k * NCB + i] = lh[i];
        return;
    }

    // ---- gemm1 branch ----
    const int r0 = blockIdx.x * 64;
    {   // stage W1 -> wsT[col][k], coalesced f32 reads, half8 writes
        int c = tid & 63, kb = tid >> 6;
        #pragma unroll
        for (int j = 0; j < 8; ++j) {
            int k8 = kb + 4 * j;
            half8 hv;
            #pragma unroll
            for (int u = 0; u < 8; ++u)
                hv[u] = (_Float16)W1[(size_t)(k8 * 8 + u) * C1 + c];
            *(half8*)(&wsT[c][k8 * 8]) = hv;
        }
    }
    __syncthreads();

    const int lane = tid & 63;
    const int wv   = tid >> 6;
    const int colb = lane & 15;
    const int rgrp = lane >> 4;
    const int arow = r0 + wv * 16 + colb;
    const bool arv = arow < NN;
    f32x4 acc[4] = {};
    #pragma unroll
    for (int s = 0; s < 8; ++s) {
        float4 v0 = make_float4(0.f,0.f,0.f,0.f), v1 = v0;
        if (arv) {
            const float4* xp = (const float4*)(&x[(size_t)arow * FIN + s * 32 + rgrp * 8]);
            v0 = xp[0]; v1 = xp[1];
        }
        half8 a;
        a[0]=(_Float16)v0.x; a[1]=(_Float16)v0.y; a[2]=(_Float16)v0.z; a[3]=(_Float16)v0.w;
        a[4]=(_Float16)v1.x; a[5]=(_Float16)v1.y; a[6]=(_Float16)v1.z; a[7]=(_Float16)v1.w;
        #pragma unroll
        for (int ct = 0; ct < 4; ++ct) {
            half8 b = *(half8*)(&wsT[ct * 16 + colb][s * 32 + rgrp * 8]);
            acc[ct] = __builtin_amdgcn_mfma_f32_16x16x32_f16(a, b, acc[ct], 0, 0, 0);
        }
    }
    __syncthreads();                    // wsT reads done; reuse as hstore
    _Float16 (*hstore)[72] = (_Float16(*)[72])wsT;
    #pragma unroll
    for (int j = 0; j < 4; ++j) {
        int row = wv * 16 + rgrp * 4 + j;
        #pragma unroll
        for (int ct = 0; ct < 4; ++ct)
            hstore[row][ct * 16 + colb] = (_Float16)acc[ct][j];
    }
    __syncthreads();
    {   // coalesced fp8 h1 store + lane-local als(fp16)/ald(f32), 2 heads/lane
        int row = tid >> 2, seg = tid & 3;
        int grow = r0 + row;
        if (grow < NN) {
            half8 h0 = *(half8*)(&hstore[row][seg * 16]);
            half8 h1v = *(half8*)(&hstore[row][seg * 16 + 8]);
            float fv[16];
            #pragma unroll
            for (int u = 0; u < 8; ++u) { fv[u] = (float)h0[u]; fv[8 + u] = (float)h1v[u]; }
            uint4 pk;
            pk.x = pack4_fp8(fv[0],  fv[1],  fv[2],  fv[3]);
            pk.y = pack4_fp8(fv[4],  fv[5],  fv[6],  fv[7]);
            pk.z = pack4_fp8(fv[8],  fv[9],  fv[10], fv[11]);
            pk.w = pack4_fp8(fv[12], fv[13], fv[14], fv[15]);
            *(uint4*)(&h1f8[(size_t)grow * 64 + seg * 16]) = pk;
            float ps0 = 0.f, pd0 = 0.f, ps1 = 0.f, pd1 = 0.f;
            #pragma unroll
            for (int u = 0; u < 8; ++u) {
                ps0 += fv[u]     * as1[seg * 16 + u];
                pd0 += fv[u]     * ad1[seg * 16 + u];
                ps1 += fv[8 + u] * as1[seg * 16 + 8 + u];
                pd1 += fv[8 + u] * ad1[seg * 16 + 8 + u];
            }
            als1h[grow * NH + seg * 2]     = (_Float16)ps0;
            als1h[grow * NH + seg * 2 + 1] = (_Float16)ps1;
            ald[grow * NH + seg * 2]     = pd0;
            ald[grow * NH + seg * 2 + 1] = pd1;
        }
    }
}

// ======== deterministic 2-pass counting sort (no global atomics) =========
// rsA: block b scans the 1024 chunk-counts of bucket b (4 per thread)
__global__ __launch_bounds__(256) void k_rsA(const int* __restrict__ H,
                                             int* __restrict__ basek,
                                             int* __restrict__ btot) {
    __shared__ int sc[256];
    int b = blockIdx.x, t = threadIdx.x;
    int loc[4];
    int tot = 0;
    #pragma unroll
    for (int j = 0; j < 4; ++j) {
        loc[j] = tot;
        tot += H[(size_t)(t * 4 + j) * NCB + b];
    }
    sc[t] = tot;
    __syncthreads();
    for (int s = 1; s < 256; s <<= 1) {
        int u = (t >= s) ? sc[t - s] : 0;
        __syncthreads();
        sc[t] += u;
        __syncthreads();
    }
    int excl = sc[t] - tot;
    #pragma unroll
    for (int j = 0; j < 4; ++j)
        basek[(size_t)b * CH + t * 4 + j] = excl + loc[j];
    if (t == 255) btot[b] = sc[t];
}

// rscatter: 1024 blocks x 512 threads; inline 512-wide bbase scan
__global__ __launch_bounds__(512) void k_rscatter(const int* __restrict__ ei,
                                                  const int* __restrict__ basek,
                                                  const int* __restrict__ btot,
                                                  int* __restrict__ stage) {
    __shared__ int sc[512];
    __shared__ int lcur[NCB];
    int k = blockIdx.x, t = threadIdx.x;
    int v = (t < NCB) ? btot[t] : 0;
    sc[t] = v;
    __syncthreads();
    for (int s = 1; s < 512; s <<= 1) {
        int u = (t >= s) ? sc[t - s] : 0;
        __syncthreads();
        sc[t] += u;
        __syncthreads();
    }
    if (t < NCB) lcur[t] = (sc[t] - v) + basek[(size_t)t * CH + k];
    __syncthreads();
    int e0 = k * EPC, e1 = min(e0 + EPC, NTOT);
    for (int e = e0 + t; e < e1; e += 512) {
        int s, d;
        if (e < NE) { s = ei[e]; d = ei[NE + e]; }
        else        { s = e - NE; d = s; }
        int pos = atomicAdd(&lcur[d >> 7], 1);
        stage[pos] = (s << 7) | (d & 127);
    }
}

// fsort: 392 blocks x 512 threads; inline bbase scan, 128-dst local sort
__global__ __launch_bounds__(512) void k_fsort(const int* __restrict__ stage,
                                               const int* __restrict__ btot,
                                               int* __restrict__ offs,
                                               int* __restrict__ ssrc) {
    __shared__ int sc[512];
    __shared__ int lc[128];
    __shared__ int ls[128];
    __shared__ int lcur[128];
    __shared__ int bb[2];
    int b = blockIdx.x, t = threadIdx.x;
    int v = (t < NCB) ? btot[t] : 0;
    sc[t] = v;
    __syncthreads();
    for (int s = 1; s < 512; s <<= 1) {
        int u = (t >= s) ? sc[t - s] : 0;
        __syncthreads();
        sc[t] += u;
        __syncthreads();
    }
    if (t == b) { bb[0] = sc[t] - v; bb[1] = sc[t]; }
    if (b == 0 && t == 0) offs[NN] = NTOT;
    if (b == 0 && t < 32) ssrc[NTOT + t] = 0;   // sentinel pad: node 0
    if (t < 128) lc[t] = 0;
    __syncthreads();
    int base = bb[0];
    int n = bb[1] - base;
    const int* sp = &stage[base];
    for (int i = t; i < n; i += 512) atomicAdd(&lc[sp[i] & 127], 1);
    __syncthreads();
    int hv = (t < 128) ? lc[t] : 0;
    if (t < 128) ls[t] = hv;
    __syncthreads();
    for (int s = 1; s < 128; s <<= 1) {
        int u = (t >= s && t < 128) ? ls[t - s] : 0;
        __syncthreads();
        if (t < 128) ls[t] += u;
        __syncthreads();
    }
    if (t < 128) {
        int excl = ls[t] - hv;
        int d = b * 128 + t;
        if (d < NN) offs[d] = base + excl;
        lcur[t] = base + excl;
    }
    __syncthreads();
    for (int i = t; i < n; i += 512) {
        int u = sp[i];
        int pos = atomicAdd(&lcur[u & 127], 1);
        ssrc[pos] = u >> 7;
    }
}

// ------- K2: layer-1 aggregation, fp8 gathers (L2-resident), packed-f32 FMA,
//             sentinel-padded src (unconditional gather addresses) ----------
__global__ __launch_bounds__(256) void k_agg1(const int* __restrict__ offs,
                                              const int* __restrict__ src,
                                              const unsigned char* __restrict__ h1f8,
                                              const _Float16* __restrict__ als1h,
                                              const float* __restrict__ ald,
                                              const float* __restrict__ b1,
                                              _Float16* __restrict__ g1h) {
    int d = blockIdx.x * 4 + (threadIdx.x >> 6);
    if (d >= NN) return;
    const int l = threadIdx.x & 63;
    const int slot = l >> 3, hd = l & 7;
    const unsigned coff = (unsigned)hd * 8u;    // byte offset in h1f8 row (64 B)
    int beg = offs[d], end = offs[d + 1];
    float aldv = ald[d * NH + hd];
    floatx2 acc2[4] = {};
    float wsum = 0.f;

    for (int r = beg; r < end; r += 16) {
        int e0 = r + slot, e1 = e0 + 8;
        int s0 = src[e0];                       // sentinel-padded: no clamp
        int s1 = src[e1];
        uint2 q0 = *(const uint2*)(h1f8 + ((unsigned)s0 * 64u + coff));
        uint2 q1 = *(const uint2*)(h1f8 + ((unsigned)s1 * 64u + coff));
        float lg0 = (float)als1h[s0 * NH + hd] + aldv;
        float lg1 = (float)als1h[s1 * NH + hd] + aldv;
        lg0 = fmaxf(lg0, 0.2f * lg0);           // leaky_relu, 1 op
        lg1 = fmaxf(lg1, 0.2f * lg1);
        float w0 = (e0 < end) ? __expf(lg0) : 0.f;
        float w1 = (e1 < end) ? __expf(lg1) : 0.f;
        wsum += w0 + w1;
        floatx2 a0, a1, a2, a3, c0, c1, c2, c3;
        cvt8_fp8_pk(q0.x, q0.y, &a0, &a1, &a2, &a3);
        cvt8_fp8_pk(q1.x, q1.y, &c0, &c1, &c2, &c3);
        floatx2 w0v = {w0, w0}, w1v = {w1, w1};
        acc2[0] += w0v * a0 + w1v * c0;
        acc2[1] += w0v * a1 + w1v * c1;
        acc2[2] += w0v * a2 + w1v * c2;
        acc2[3] += w0v * a3 + w1v * c3;
    }
    float acc[8];
    #pragma unroll
    for (int u = 0; u < 4; ++u) { acc[2*u] = acc2[u][0]; acc[2*u+1] = acc2[u][1]; }
    #pragma unroll
    for (int u = 0; u < 8; ++u) {
        acc[u] += __shfl_xor(acc[u], 8);
        acc[u] += __shfl_xor(acc[u], 16);
        acc[u] += __shfl_xor(acc[u], 32);
    }
    wsum += __shfl_xor(wsum, 8);
    wsum += __shfl_xor(wsum, 16);
    wsum += __shfl_xor(wsum, 32);
    if (slot == 0) {
        half8 gv;
        #pragma unroll
        for (int u = 0; u < 8; ++u) {
            float o = acc[u] / wsum + b1[hd * 8 + u];
            o = o > 0.f ? o : (__expf(o) - 1.f);
            gv[u] = (_Float16)o;
        }
        *(half8*)(&g1h[(size_t)d * C1 + hd * 8]) = gv;
    }
}

// ---------------- K3: GEMM2 (64->16, fp16 in) + layer-2 logits ----------------
__global__ __launch_bounds__(256) void k_gemm2(const _Float16* __restrict__ g1h,
                                               const float* __restrict__ W2,
                                               const float* __restrict__ as2,
                                               const float* __restrict__ ad2,
                                               _Float16* __restrict__ h2h,
                                               float* __restrict__ als2,
                                               float* __restrict__ ald2) {
    __shared__ float w2s[C1][17];
    __shared__ _Float16 hact[16][C1 + 8];
    int tid = threadIdx.x;
    for (int i = tid; i < C1 * NC; i += 256) w2s[i >> 4][i & 15] = W2[i];
    int ln = tid >> 4, j = tid & 15;
    int n = blockIdx.x * 16 + ln;
    if (n < NN)
        *(half4*)(&hact[ln][j * 4]) = *(const half4*)(&g1h[(size_t)n * C1 + j * 4]);
    __syncthreads();
    if (n >= NN) return;
    float sum = 0.f;
    #pragma unroll
    for (int c = 0; c < C1; ++c) sum += (float)hact[ln][c] * w2s[c][j];
    h2h[(size_t)n * NC + j] = (_Float16)sum;
    float ps = sum * as2[j], pd = sum * ad2[j];
    #pragma unroll
    for (int w = 1; w < 16; w <<= 1) {
        ps += __shfl_xor(ps, w);
        pd += __shfl_xor(pd, w);
    }
    if (j == 0) { als2[n] = ps; ald2[n] = pd; }
}

// ------- K4: layer-2 aggregation, shuffle-free, sentinel-padded src,
//             fused log_softmax --------------------------------------------
__global__ __launch_bounds__(256) void k_agg2(const int* __restrict__ offs,
                                              const int* __restrict__ src,
                                              const _Float16* __restrict__ h2h,
                                              const float* __restrict__ als2,
                                              const float* __restrict__ ald2,
                                              const float* __restrict__ b2,
                                              float* __restrict__ out) {
    int d = blockIdx.x * 4 + (threadIdx.x >> 6);
    if (d >= NN) return;
    const int l = threadIdx.x & 63;
    const int slot = l >> 2, cq = l & 3;
    const unsigned coff = (unsigned)cq * 8u;
    const char* h2b = (const char*)h2h;
    const char* alb = (const char*)als2;
    int beg = offs[d], end = offs[d + 1];
    float aldv = ald2[d];
    float acc[4] = {};
    float wsum = 0.f;
    for (int r = beg; r < end; r += 16) {
        int e = r + slot;
        int s = src[e];                          // sentinel-padded: no clamp
        half4 hv = *(const half4*)(h2b + ((unsigned)s * 32u + coff));
        float lg = *(const float*)(alb + (unsigned)s * 4u) + aldv;
        lg = fmaxf(lg, 0.2f * lg);
        float w = (e < end) ? __expf(lg) : 0.f;
        wsum += w;
        #pragma unroll
        for (int u = 0; u < 4; ++u)
            acc[u] += w * (float)hv[u];
    }
    #pragma unroll
    for (int u = 0; u < 4; ++u) {
        acc[u] += __shfl_xor(acc[u], 4);
        acc[u] += __shfl_xor(acc[u], 8);
        acc[u] += __shfl_xor(acc[u], 16);
        acc[u] += __shfl_xor(acc[u], 32);
    }
    wsum += __shfl_xor(wsum, 4);
    wsum += __shfl_xor(wsum, 8);
    wsum += __shfl_xor(wsum, 16);
    wsum += __shfl_xor(wsum, 32);
    float o[4];
    float m = -1e30f;
    #pragma unroll
    for (int u = 0; u < 4; ++u) {
        o[u] = acc[u] / wsum + b2[cq * 4 + u];
        m = fmaxf(m, o[u]);
    }
    m = fmaxf(m, __shfl_xor(m, 1));
    m = fmaxf(m, __shfl_xor(m, 2));
    float sm = 0.f;
    #pragma unroll
    for (int u = 0; u < 4; ++u) sm += __expf(o[u] - m);
    sm += __shfl_xor(sm, 1);
    sm += __shfl_xor(sm, 2);
    float lse = m + __logf(sm);
    if (slot == 0) {
        float4 ov = make_float4(o[0] - lse, o[1] - lse, o[2] - lse, o[3] - lse);
        *(float4*)(&out[(size_t)d * NC + cq * 4]) = ov;
    }
}

extern "C" void kernel_launch(void* const* d_in, const int* in_sizes, int n_in,
                              void* d_out, int out_size, void* d_ws, size_t ws_size,
                              hipStream_t stream) {
    const float* x   = (const float*)d_in[0];
    const int*   ei  = (const int*)  d_in[1];
    const float* W1  = (const float*)d_in[2];
    const float* as1 = (const float*)d_in[3];
    const float* ad1 = (const float*)d_in[4];
    const float* b1  = (const float*)d_in[5];
    const float* W2  = (const float*)d_in[6];
    const float* as2 = (const float*)d_in[7];
    const float* ad2 = (const float*)d_in[8];
    const float* b2  = (const float*)d_in[9];
    float* ws  = (float*)d_ws;
    float* out = (float*)d_out;

    unsigned char* h1f8 = (unsigned char*)(ws + OFF_H1F8);
    _Float16*  als1h = (_Float16*)(ws + OFF_ALS1H);
    _Float16*  g1h  = (_Float16*)(ws + OFF_G1H);
    _Float16*  h2h  = (_Float16*)(ws + OFF_H2H);
    float* ald1 = ws + OFF_ALD1;
    float* als2 = ws + OFF_ALS2;
    float* ald2 = ws + OFF_ALD2;
    int* H      = (int*)(ws + OFF_HM);
    int* basek  = (int*)(ws + OFF_BASEK);
    int* btot   = (int*)(ws + OFF_BTOT);
    int* offs   = (int*)(ws + OFF_OFFS);
    int* ssrc   = (int*)(ws + OFF_SRC);
    int* stage  = (int*)(ws + OFF_STAGE);

    k_g1rh    <<<GB1 + CH,       256, 0, stream>>>(x, W1, as1, ad1, h1f8, als1h, ald1, ei, H);
    k_rsA     <<<NCB,            256, 0, stream>>>(H, basek, btot);
    k_rscatter<<<CH,             512, 0, stream>>>(ei, basek, btot, stage);
    k_fsort   <<<NCB,            512, 0, stream>>>(stage, btot, offs, ssrc);
    k_agg1    <<<(NN + 3) / 4,   256, 0, stream>>>(offs, ssrc, h1f8, als1h, ald1, b1, g1h);
    k_gemm2   <<<(NN + 15) / 16, 256, 0, stream>>>(g1h, W2, as2, ad2, h2h, als2, ald2);
    k_agg2    <<<(NN + 3) / 4,   256, 0, stream>>>(offs, ssrc, h2h, als2, ald2, b2, out);
}